// Round 1
// baseline (940.825 us; speedup 1.0000x reference)
//
#include <hip/hip_runtime.h>
#include <hip/hip_bf16.h>

#define NPOS 6912
#define HW   2304
#define C    256
#define EPSG 1e-6f
// softmax scale folded with log2(e): exp(s*0.0625) = exp2(s*K2)
#define K2 (0.0625f * 1.4426950408889634f)

typedef __attribute__((ext_vector_type(8))) short bf16x8;  // 8 bf16 in 4 VGPRs
typedef __attribute__((ext_vector_type(4))) float f32x4;

__device__ __forceinline__ unsigned short f2bf(float f) {
    union { float f; unsigned int u; } v; v.f = f;
    unsigned int lsb = (v.u >> 16) & 1u;
    return (unsigned short)((v.u + 0x7fffu + lsb) >> 16);
}

#define MFMA(a, b, c) __builtin_amdgcn_mfma_f32_16x16x32_bf16((a), (b), (c), 0, 0, 0)

// ---------------- weights fp32 -> bf16 ----------------
__global__ void wconv(const float* wq, const float* wk, const float* wv, const float* wp,
                      unsigned short* wbf) {
    int i = blockIdx.x * 256 + threadIdx.x;        // 0..65535
    wbf[i]           = f2bf(wq[i]);
    wbf[65536 + i]   = f2bf(wk[i]);
    wbf[131072 + i]  = f2bf(wv[i]);
    wbf[196608 + i]  = f2bf(wp[i]);
}

// ---------------- GroupNorm stats (deterministic 2-stage) ----------------
__global__ __launch_bounds__(256) void gn_stats(const float* x, float* part) {
    int gid = blockIdx.x >> 5, slice = blockIdx.x & 31; // 8 groups x 32 slices
    int b = gid >> 2, grp = gid & 3;
    float s = 0.f, s2 = 0.f;
    for (int k = 0; k < 54; ++k) {
        int e = slice * 13824 + k * 256 + (int)threadIdx.x;   // 0..442367 per group
        int f = e / 147456; int r1 = e - f * 147456;
        int ch = r1 / HW;   int sp = r1 - ch * HW;
        float v = x[(size_t)((f * 2 + b) * C + grp * 64 + ch) * HW + sp];
        s += v; s2 += v * v;
    }
    #pragma unroll
    for (int off = 32; off; off >>= 1) { s += __shfl_xor(s, off); s2 += __shfl_xor(s2, off); }
    __shared__ float ls[8];
    int w = threadIdx.x >> 6;
    if ((threadIdx.x & 63) == 0) { ls[w * 2] = s; ls[w * 2 + 1] = s2; }
    __syncthreads();
    if (threadIdx.x == 0) {
        float t = 0.f, t2 = 0.f;
        for (int i = 0; i < 4; ++i) { t += ls[i * 2]; t2 += ls[i * 2 + 1]; }
        part[blockIdx.x * 2] = t; part[blockIdx.x * 2 + 1] = t2;
    }
}

__global__ void gn_fin(const float* part, float* stats) {
    int g = threadIdx.x; if (g >= 8) return;
    float s = 0.f, s2 = 0.f;
    for (int i = 0; i < 32; ++i) { s += part[(g * 32 + i) * 2]; s2 += part[(g * 32 + i) * 2 + 1]; }
    float mean = s / 442368.f;
    float var  = s2 / 442368.f - mean * mean;
    stats[g * 2] = mean; stats[g * 2 + 1] = rsqrtf(var + EPSG);
}

// ---------------- GN apply -> Hn (b, n, c) bf16, LDS transpose ----------------
__global__ __launch_bounds__(256) void gn_apply(const float* x, const float* stats,
                                                const float* gsc, const float* gbi,
                                                unsigned short* hn) {
    int blk = blockIdx.x;                 // 2*3*48 = 288
    int b = blk / 144; int f = (blk % 144) / 48; int y = blk % 48;
    int c = threadIdx.x;
    int gid = b * 4 + (c >> 6);
    float mean = stats[gid * 2], rsig = stats[gid * 2 + 1];
    float sc = gsc[c] * rsig, bi = gbi[c] - mean * sc;
    __shared__ unsigned short lds[48 * 256];
    const float* xr = x + (size_t)((f * 2 + b) * C + c) * HW + y * 48;
    #pragma unroll
    for (int xw = 0; xw < 48; xw += 4) {
        float4 v = *(const float4*)(xr + xw);
        lds[(xw + 0) * 256 + c] = f2bf(v.x * sc + bi);
        lds[(xw + 1) * 256 + c] = f2bf(v.y * sc + bi);
        lds[(xw + 2) * 256 + c] = f2bf(v.z * sc + bi);
        lds[(xw + 3) * 256 + c] = f2bf(v.w * sc + bi);
    }
    __syncthreads();
    size_t base = ((size_t)b * NPOS + f * HW + y * 48) * C;
    for (int xw = 0; xw < 48; ++xw)
        hn[base + (size_t)xw * C + threadIdx.x] = lds[xw * 256 + threadIdx.x];
}

// ---------------- Q/K GEMM: out(b,n,c) = Hn(b,n,c) x W^T + bias ----------------
__global__ __launch_bounds__(256) void qk_gemm(const unsigned short* hn, const unsigned short* wbf,
                                               const float* bq, const float* bk,
                                               unsigned short* qt, unsigned short* kt) {
    int t = blockIdx.x;                  // 2 sel * 2 b * 108 pt * 4 ot = 1728
    int sel = t / 864; int rem = t % 864;
    int b = rem / 432;  int rem2 = rem % 432;
    int pt = rem2 >> 2; int ot = rem2 & 3;
    int lane = threadIdx.x & 63, w = threadIdx.x >> 6;
    int l16 = lane & 15, g = lane >> 4;
    const unsigned short* wsel = wbf + sel * 65536;
    const float* bias = sel ? bk : bq;
    unsigned short* out = sel ? kt : qt;
    const unsigned short* arow = hn + ((size_t)b * NPOS + pt * 64 + w * 16 + l16) * C + g * 8;
    const unsigned short* brow = wsel + (ot * 64 + l16) * C + g * 8;
    f32x4 acc[4] = {{0.f,0.f,0.f,0.f},{0.f,0.f,0.f,0.f},{0.f,0.f,0.f,0.f},{0.f,0.f,0.f,0.f}};
    #pragma unroll
    for (int kk = 0; kk < 8; ++kk) {
        bf16x8 a = *(const bf16x8*)(arow + kk * 32);
        #pragma unroll
        for (int f = 0; f < 4; ++f) {
            bf16x8 bb = *(const bf16x8*)(brow + f * 16 * C + kk * 32);
            acc[f] = MFMA(a, bb, acc[f]);
        }
    }
    size_t obase = ((size_t)b * NPOS + pt * 64 + w * 16) * C + ot * 64;
    #pragma unroll
    for (int f = 0; f < 4; ++f) {
        float bv = bias[ot * 64 + f * 16 + l16];
        #pragma unroll
        for (int r = 0; r < 4; ++r)
            out[obase + (size_t)(4 * g + r) * C + f * 16 + l16] = f2bf(acc[f][r] + bv);
    }
}

// ---------------- V GEMM: V(b,c,n) = Wv x Hn^T + bias ----------------
__global__ __launch_bounds__(256) void v_gemm(const unsigned short* hn, const unsigned short* wbf,
                                              const float* bvp, unsigned short* vv) {
    int t = blockIdx.x;                  // 2 b * 4 ot * 108 pt = 864
    int b = t / 432; int rem2 = t % 432;
    int ot = rem2 / 108; int pt = rem2 % 108;
    int lane = threadIdx.x & 63, w = threadIdx.x >> 6;
    int l16 = lane & 15, g = lane >> 4;
    const unsigned short* wvw = wbf + 131072;
    const unsigned short* arow = wvw + (ot * 64 + w * 16 + l16) * C + g * 8;
    const unsigned short* brow = hn + ((size_t)b * NPOS + pt * 64 + l16) * C + g * 8;
    f32x4 acc[4] = {{0.f,0.f,0.f,0.f},{0.f,0.f,0.f,0.f},{0.f,0.f,0.f,0.f},{0.f,0.f,0.f,0.f}};
    #pragma unroll
    for (int kk = 0; kk < 8; ++kk) {
        bf16x8 a = *(const bf16x8*)(arow + kk * 32);
        #pragma unroll
        for (int f = 0; f < 4; ++f) {
            bf16x8 bb = *(const bf16x8*)(brow + f * 16 * C + kk * 32);
            acc[f] = MFMA(a, bb, acc[f]);
        }
    }
    #pragma unroll
    for (int f = 0; f < 4; ++f) {
        #pragma unroll
        for (int r = 0; r < 4; ++r) {
            int o = ot * 64 + w * 16 + 4 * g + r;
            vv[((size_t)b * C + o) * NPOS + pt * 64 + f * 16 + l16] = f2bf(acc[f][r] + bvp[o]);
        }
    }
}

// ---------------- flash attention: O(b,n,c) bf16 ----------------
__global__ __launch_bounds__(256) void flash(const unsigned short* qt, const unsigned short* kt,
                                             const unsigned short* vv, unsigned short* oo) {
    int blk = blockIdx.x;                         // 216, 216%8==0 -> bijective XCD swizzle
    int lid = (blk & 7) * 27 + (blk >> 3);
    int b = lid / 108, qtile = lid % 108;
    int lane = threadIdx.x & 63, w = threadIdx.x >> 6;
    int l16 = lane & 15, g = lane >> 4;
    const unsigned short* Qb = qt + (size_t)b * NPOS * C;
    const unsigned short* Kb = kt + (size_t)b * NPOS * C;
    const unsigned short* Vb = vv + (size_t)b * C * NPOS;
    int i0 = qtile * 64 + w * 16;                 // this wave's 16 query rows
    bf16x8 qf[8];
    #pragma unroll
    for (int kk = 0; kk < 8; ++kk)
        qf[kk] = *(const bf16x8*)(Qb + (size_t)(i0 + l16) * C + kk * 32 + g * 8);
    f32x4 oacc[16];
    #pragma unroll
    for (int cf = 0; cf < 16; ++cf) oacc[cf] = (f32x4){0.f,0.f,0.f,0.f};
    float m[4], lsum[4];
    #pragma unroll
    for (int r = 0; r < 4; ++r) { m[r] = -INFINITY; lsum[r] = 0.f; }
    __shared__ unsigned short plds[4][16][80];    // per-wave P tile, padded rows

    for (int jt = 0; jt < 108; ++jt) {
        int j0 = jt * 64;
        f32x4 s[4];
        #pragma unroll
        for (int f = 0; f < 4; ++f) s[f] = (f32x4){0.f,0.f,0.f,0.f};
        const unsigned short* kbase = Kb + (size_t)(j0 + l16) * C + g * 8;
        #pragma unroll
        for (int kk = 0; kk < 8; ++kk) {
            #pragma unroll
            for (int f = 0; f < 4; ++f) {
                bf16x8 bb = *(const bf16x8*)(kbase + (size_t)f * 16 * C + kk * 32);
                s[f] = MFMA(qf[kk], bb, s[f]);
            }
        }
        // online softmax over this wave's rows (row = 4*g + r, lane group reduce)
        float pmax[4];
        #pragma unroll
        for (int r = 0; r < 4; ++r) {
            float mx = fmaxf(fmaxf(s[0][r], s[1][r]), fmaxf(s[2][r], s[3][r]));
            #pragma unroll
            for (int off = 1; off < 16; off <<= 1) mx = fmaxf(mx, __shfl_xor(mx, off));
            pmax[r] = mx;
        }
        bool upd = false;
        #pragma unroll
        for (int r = 0; r < 4; ++r) if ((pmax[r] - m[r]) * K2 > 8.f) upd = true;
        if (__any(upd)) {                          // T13 defer-max: rescale rarely
            #pragma unroll
            for (int r = 0; r < 4; ++r) {
                float mn = fmaxf(m[r], pmax[r]);
                float al = __builtin_amdgcn_exp2f((m[r] - mn) * K2);
                m[r] = mn; lsum[r] *= al;
                #pragma unroll
                for (int cf = 0; cf < 16; ++cf) oacc[cf][r] *= al;
            }
        }
        #pragma unroll
        for (int r = 0; r < 4; ++r) {
            float rs = 0.f;
            #pragma unroll
            for (int f = 0; f < 4; ++f) {
                float p = __builtin_amdgcn_exp2f((s[f][r] - m[r]) * K2);
                plds[w][4 * g + r][f * 16 + l16] = f2bf(p);
                rs += p;
            }
            #pragma unroll
            for (int off = 1; off < 16; off <<= 1) rs += __shfl_xor(rs, off);
            lsum[r] += rs;
        }
        // PV: O += P * V^T   (A = P from private LDS, B = V rows contiguous)
        #pragma unroll
        for (int kk2 = 0; kk2 < 2; ++kk2) {
            bf16x8 pa = *(const bf16x8*)(&plds[w][l16][kk2 * 32 + g * 8]);
            const unsigned short* vbase = Vb + (size_t)l16 * NPOS + j0 + kk2 * 32 + g * 8;
            #pragma unroll
            for (int cf = 0; cf < 16; ++cf) {
                bf16x8 vb = *(const bf16x8*)(vbase + (size_t)cf * 16 * NPOS);
                oacc[cf] = MFMA(pa, vb, oacc[cf]);
            }
        }
    }
    float inv[4];
    #pragma unroll
    for (int r = 0; r < 4; ++r) inv[r] = 1.f / lsum[r];
    size_t obase = ((size_t)b * NPOS + i0) * C;
    #pragma unroll
    for (int cf = 0; cf < 16; ++cf)
        #pragma unroll
        for (int r = 0; r < 4; ++r)
            oo[obase + (size_t)(4 * g + r) * C + cf * 16 + l16] = f2bf(oacc[cf][r] * inv[r]);
}

// ---------------- proj + bias + residual, coalesced via LDS transpose ----------------
__global__ __launch_bounds__(256) void proj(const unsigned short* oo, const unsigned short* wbf,
                                            const float* bp, const float* x, float* out) {
    int t = blockIdx.x;                  // 2 b * 108 pt * 4 ot = 864
    int b = t / 432; int rem2 = t % 432;
    int pt = rem2 >> 2; int ot = rem2 & 3;
    int lane = threadIdx.x & 63, w = threadIdx.x >> 6;
    int l16 = lane & 15, g = lane >> 4;
    const unsigned short* wpw = wbf + 196608;
    const unsigned short* arow = oo + ((size_t)b * NPOS + pt * 64 + w * 16 + l16) * C + g * 8;
    const unsigned short* brow = wpw + (ot * 64 + l16) * C + g * 8;
    f32x4 acc[4] = {{0.f,0.f,0.f,0.f},{0.f,0.f,0.f,0.f},{0.f,0.f,0.f,0.f},{0.f,0.f,0.f,0.f}};
    #pragma unroll
    for (int kk = 0; kk < 8; ++kk) {
        bf16x8 a = *(const bf16x8*)(arow + kk * 32);
        #pragma unroll
        for (int f = 0; f < 4; ++f) {
            bf16x8 bb = *(const bf16x8*)(brow + f * 16 * C + kk * 32);
            acc[f] = MFMA(a, bb, acc[f]);
        }
    }
    __shared__ float lt[64][72];
    #pragma unroll
    for (int f = 0; f < 4; ++f) {
        float bv = bp[ot * 64 + f * 16 + l16];
        #pragma unroll
        for (int r = 0; r < 4; ++r)
            lt[f * 16 + l16][w * 16 + 4 * g + r] = acc[f][r] + bv;
    }
    __syncthreads();
    int p0 = pt * 64;
    int f3 = p0 / HW; int sp0 = p0 - f3 * HW;     // 64 | 2304 so whole tile same f
    for (int it = 0; it < 16; ++it) {
        int ol = it * 4 + w;
        int pl = lane;
        size_t idx = ((size_t)(b * 3 + f3) * C + ot * 64 + ol) * HW + sp0 + pl;
        out[idx] = x[idx] + lt[ol][pl];
    }
}

extern "C" void kernel_launch(void* const* d_in, const int* in_sizes, int n_in,
                              void* d_out, int out_size, void* d_ws, size_t ws_size,
                              hipStream_t stream) {
    const float* x   = (const float*)d_in[0];
    const float* gsc = (const float*)d_in[1];
    const float* gbi = (const float*)d_in[2];
    const float* wq  = (const float*)d_in[3];
    const float* bq  = (const float*)d_in[4];
    const float* wk  = (const float*)d_in[5];
    const float* bk  = (const float*)d_in[6];
    const float* wv  = (const float*)d_in[7];
    const float* bv  = (const float*)d_in[8];
    const float* wp  = (const float*)d_in[9];
    const float* bp  = (const float*)d_in[10];

    char* ws = (char*)d_ws;
    unsigned short* wbf = (unsigned short*)(ws);             // 524288 B
    float* stats        = (float*)(ws + 524288);             // 64 B
    float* part         = (float*)(ws + 528384);             // 2048 B
    unsigned short* hn  = (unsigned short*)(ws + 532480);    // 7077888 B
    unsigned short* qt  = (unsigned short*)(ws + 7610368);   // 7077888 B
    unsigned short* kt  = (unsigned short*)(ws + 14688256);  // 7077888 B
    unsigned short* vv  = (unsigned short*)(ws + 21766144);  // 7077888 B
    unsigned short* oo  = (unsigned short*)(ws + 28844032);  // 7077888 B
    float* out = (float*)d_out;

    hipLaunchKernelGGL(wconv,    dim3(256),  dim3(256), 0, stream, wq, wk, wv, wp, wbf);
    hipLaunchKernelGGL(gn_stats, dim3(256),  dim3(256), 0, stream, x, part);
    hipLaunchKernelGGL(gn_fin,   dim3(1),    dim3(64),  0, stream, part, stats);
    hipLaunchKernelGGL(gn_apply, dim3(288),  dim3(256), 0, stream, x, stats, gsc, gbi, hn);
    hipLaunchKernelGGL(qk_gemm,  dim3(1728), dim3(256), 0, stream, hn, wbf, bq, bk, qt, kt);
    hipLaunchKernelGGL(v_gemm,   dim3(864),  dim3(256), 0, stream, hn, wbf, bv, vv);
    hipLaunchKernelGGL(flash,    dim3(216),  dim3(256), 0, stream, qt, kt, vv, oo);
    hipLaunchKernelGGL(proj,     dim3(864),  dim3(256), 0, stream, oo, wbf, bp, x, out);
}

// Round 2
// 336.485 us; speedup vs baseline: 2.7960x; 2.7960x over previous
//
#include <hip/hip_runtime.h>
#include <hip/hip_bf16.h>

#define NPOS 6912
#define HW   2304
#define C    256
#define EPSG 1e-6f
// softmax scale folded with log2(e): exp(s*0.0625) = exp2(s*K2)
#define K2 (0.0625f * 1.4426950408889634f)

typedef __attribute__((ext_vector_type(8))) short bf16x8;  // 8 bf16 in 4 VGPRs
typedef __attribute__((ext_vector_type(4))) float f32x4;
typedef long long i64;
typedef unsigned char u8;

__device__ __forceinline__ unsigned short f2bf(float f) {
    union { float f; unsigned int u; } v; v.f = f;
    unsigned int lsb = (v.u >> 16) & 1u;
    return (unsigned short)((v.u + 0x7fffu + lsb) >> 16);
}

// f32 -> fp8 e4m3fn (OCP), RNE, with subnormal handling. |f| <= ~3 here.
__device__ __forceinline__ u8 f2fp8(float f) {
    union { float f; unsigned u; } v; v.f = f;
    unsigned sgn = (v.u >> 24) & 0x80u;
    unsigned a = v.u & 0x7FFFFFFFu;
    if (a >= 0x3C800000u) {                       // |f| >= 2^-6 : normal
        unsigned r = a + 0x000FFFFFu + ((a >> 20) & 1u);
        return (u8)(sgn | ((r >> 20) - 0x3C0u));
    }
    union { unsigned u; float f; } w2; w2.u = a;
    int mnt = (int)rintf(w2.f * 512.0f);          // subnormal: step 2^-9
    return (u8)(sgn | (unsigned)mnt);
}

// hot path: p >= 0, p <= 256; flush < 2^-6 (negligible softmax weight)
__device__ __forceinline__ u8 p2fp8(float p) {
    union { float f; unsigned u; } v; v.f = p;
    if (v.u < 0x3C800000u) return 0;
    unsigned r = v.u + 0x000FFFFFu + ((v.u >> 20) & 1u);
    return (u8)((r >> 20) - 0x3C0u);
}

#define MFMA(a, b, c)  __builtin_amdgcn_mfma_f32_16x16x32_bf16((a), (b), (c), 0, 0, 0)
#define MFMA8(a, b, c) __builtin_amdgcn_mfma_f32_16x16x32_fp8_fp8((a), (b), (c), 0, 0, 0)

// async global->LDS, 16B per lane; dest must be wave-uniform base (lane*16 implicit)
__device__ __forceinline__ void gld16(const u8* g, const char* l) {
    __builtin_amdgcn_global_load_lds(
        (const __attribute__((address_space(1))) void*)(unsigned long long)g,
        (__attribute__((address_space(3))) void*)(unsigned int)(unsigned long long)l,
        16, 0, 0);
}

// ---------------- weights fp32 -> bf16 ----------------
__global__ void wconv(const float* wq, const float* wk, const float* wv, const float* wp,
                      unsigned short* wbf) {
    int i = blockIdx.x * 256 + threadIdx.x;        // 0..65535
    wbf[i]           = f2bf(wq[i]);
    wbf[65536 + i]   = f2bf(wk[i]);
    wbf[131072 + i]  = f2bf(wv[i]);
    wbf[196608 + i]  = f2bf(wp[i]);
}

// ---------------- GroupNorm stats (deterministic 2-stage) ----------------
__global__ __launch_bounds__(256) void gn_stats(const float* x, float* part) {
    int gid = blockIdx.x >> 5, slice = blockIdx.x & 31; // 8 groups x 32 slices
    int b = gid >> 2, grp = gid & 3;
    float s = 0.f, s2 = 0.f;
    for (int k = 0; k < 54; ++k) {
        int e = slice * 13824 + k * 256 + (int)threadIdx.x;   // 0..442367 per group
        int f = e / 147456; int r1 = e - f * 147456;
        int ch = r1 / HW;   int sp = r1 - ch * HW;
        float v = x[(size_t)((f * 2 + b) * C + grp * 64 + ch) * HW + sp];
        s += v; s2 += v * v;
    }
    #pragma unroll
    for (int off = 32; off; off >>= 1) { s += __shfl_xor(s, off); s2 += __shfl_xor(s2, off); }
    __shared__ float ls[8];
    int w = threadIdx.x >> 6;
    if ((threadIdx.x & 63) == 0) { ls[w * 2] = s; ls[w * 2 + 1] = s2; }
    __syncthreads();
    if (threadIdx.x == 0) {
        float t = 0.f, t2 = 0.f;
        for (int i = 0; i < 4; ++i) { t += ls[i * 2]; t2 += ls[i * 2 + 1]; }
        part[blockIdx.x * 2] = t; part[blockIdx.x * 2 + 1] = t2;
    }
}

__global__ void gn_fin(const float* part, float* stats) {
    int g = threadIdx.x; if (g >= 8) return;
    float s = 0.f, s2 = 0.f;
    for (int i = 0; i < 32; ++i) { s += part[(g * 32 + i) * 2]; s2 += part[(g * 32 + i) * 2 + 1]; }
    float mean = s / 442368.f;
    float var  = s2 / 442368.f - mean * mean;
    stats[g * 2] = mean; stats[g * 2 + 1] = rsqrtf(var + EPSG);
}

// ---------------- GN apply -> Hn (b, n, c) bf16, LDS transpose ----------------
__global__ __launch_bounds__(256) void gn_apply(const float* x, const float* stats,
                                                const float* gsc, const float* gbi,
                                                unsigned short* hn) {
    int blk = blockIdx.x;                 // 2*3*48 = 288
    int b = blk / 144; int f = (blk % 144) / 48; int y = blk % 48;
    int c = threadIdx.x;
    int gid = b * 4 + (c >> 6);
    float mean = stats[gid * 2], rsig = stats[gid * 2 + 1];
    float sc = gsc[c] * rsig, bi = gbi[c] - mean * sc;
    __shared__ unsigned short lds[48 * 256];
    const float* xr = x + (size_t)((f * 2 + b) * C + c) * HW + y * 48;
    #pragma unroll
    for (int xw = 0; xw < 48; xw += 4) {
        float4 v = *(const float4*)(xr + xw);
        lds[(xw + 0) * 256 + c] = f2bf(v.x * sc + bi);
        lds[(xw + 1) * 256 + c] = f2bf(v.y * sc + bi);
        lds[(xw + 2) * 256 + c] = f2bf(v.z * sc + bi);
        lds[(xw + 3) * 256 + c] = f2bf(v.w * sc + bi);
    }
    __syncthreads();
    size_t base = ((size_t)b * NPOS + f * HW + y * 48) * C;
    for (int xw = 0; xw < 48; ++xw)
        hn[base + (size_t)xw * C + threadIdx.x] = lds[xw * 256 + threadIdx.x];
}

// ---------------- Q/K GEMM: out(b,n,c) fp8 = Hn(b,n,c) x W^T + bias ----------------
__global__ __launch_bounds__(256) void qk_gemm(const unsigned short* hn, const unsigned short* wbf,
                                               const float* bq, const float* bk,
                                               u8* qfp, u8* kfp) {
    int t = blockIdx.x;                  // 2 sel * 2 b * 108 pt * 4 ot = 1728
    int sel = t / 864; int rem = t % 864;
    int b = rem / 432;  int rem2 = rem % 432;
    int pt = rem2 >> 2; int ot = rem2 & 3;
    int lane = threadIdx.x & 63, w = threadIdx.x >> 6;
    int l16 = lane & 15, g = lane >> 4;
    const unsigned short* wsel = wbf + sel * 65536;
    const float* bias = sel ? bk : bq;
    u8* out = sel ? kfp : qfp;
    const unsigned short* arow = hn + ((size_t)b * NPOS + pt * 64 + w * 16 + l16) * C + g * 8;
    const unsigned short* brow = wsel + (ot * 64 + l16) * C + g * 8;
    f32x4 acc[4] = {{0.f,0.f,0.f,0.f},{0.f,0.f,0.f,0.f},{0.f,0.f,0.f,0.f},{0.f,0.f,0.f,0.f}};
    #pragma unroll
    for (int kk = 0; kk < 8; ++kk) {
        bf16x8 a = *(const bf16x8*)(arow + kk * 32);
        #pragma unroll
        for (int f = 0; f < 4; ++f) {
            bf16x8 bb = *(const bf16x8*)(brow + f * 16 * C + kk * 32);
            acc[f] = MFMA(a, bb, acc[f]);
        }
    }
    size_t obase = ((size_t)b * NPOS + pt * 64 + w * 16) * C + ot * 64;
    #pragma unroll
    for (int f = 0; f < 4; ++f) {
        float bv = bias[ot * 64 + f * 16 + l16];
        #pragma unroll
        for (int r = 0; r < 4; ++r)
            out[obase + (size_t)(4 * g + r) * C + f * 16 + l16] = f2fp8(acc[f][r] + bv);
    }
}

// ---------------- V GEMM: V(b,c,n) fp8 = Wv x Hn^T + bias ----------------
__global__ __launch_bounds__(256) void v_gemm(const unsigned short* hn, const unsigned short* wbf,
                                              const float* bvp, u8* vfp) {
    int t = blockIdx.x;                  // 2 b * 4 ot * 108 pt = 864
    int b = t / 432; int rem2 = t % 432;
    int ot = rem2 / 108; int pt = rem2 % 108;
    int lane = threadIdx.x & 63, w = threadIdx.x >> 6;
    int l16 = lane & 15, g = lane >> 4;
    const unsigned short* wvw = wbf + 131072;
    const unsigned short* arow = wvw + (ot * 64 + w * 16 + l16) * C + g * 8;
    const unsigned short* brow = hn + ((size_t)b * NPOS + pt * 64 + l16) * C + g * 8;
    f32x4 acc[4] = {{0.f,0.f,0.f,0.f},{0.f,0.f,0.f,0.f},{0.f,0.f,0.f,0.f},{0.f,0.f,0.f,0.f}};
    #pragma unroll
    for (int kk = 0; kk < 8; ++kk) {
        bf16x8 a = *(const bf16x8*)(arow + kk * 32);
        #pragma unroll
        for (int f = 0; f < 4; ++f) {
            bf16x8 bb = *(const bf16x8*)(brow + f * 16 * C + kk * 32);
            acc[f] = MFMA(a, bb, acc[f]);
        }
    }
    #pragma unroll
    for (int f = 0; f < 4; ++f) {
        #pragma unroll
        for (int r = 0; r < 4; ++r) {
            int o = ot * 64 + w * 16 + 4 * g + r;
            vfp[((size_t)b * C + o) * NPOS + pt * 64 + f * 16 + l16] = f2fp8(acc[f][r] + bvp[o]);
        }
    }
}

// ---------------- flash attention (fp8), LDS-staged K/V, in-block KV split ----------------
// 216 blocks x 512 threads. blk%8 -> XCD; batch pinned to XCD half (K+V fp8 = 3.54MB < 4MB L2).
// 8 waves: wave w: split sp=w>>2 (KV half), q-group qg=w&3 (16 q rows). Double-buffered LDS:
// per (split,buf): K tile 64x256 fp8 (16KB, 16B-unit XOR swizzle keyed row&7) +
//                  V tile 256x64 fp8 (16KB, swizzle keyed c&3). Staging via global_load_lds
// with pre-swizzled per-lane global source (rule #21: swizzle both sides or neither).
#define SMEM_BYTES 141312
#define PLDS_OFF   131072
#define SM_OFF     140288

__global__ __launch_bounds__(512) void flash(const u8* qf, const u8* kf, const u8* vf,
                                             unsigned short* oo) {
    __shared__ char smem[SMEM_BYTES];
    int blk = blockIdx.x;
    int x = blk & 7, t = blk >> 3;                // x = XCD slot
    int b = x >> 2, qtile = t * 4 + (x & 3);      // batch pinned to XCD half
    int tid = (int)threadIdx.x;
    int lane = tid & 63, w = tid >> 6;
    int l16 = lane & 15, g = lane >> 4;
    int sp = w >> 2, qg = w & 3;
    int i0 = qtile * 64 + qg * 16;

    const u8* Qb = qf + (size_t)b * (NPOS * 256);
    const u8* Kb = kf + (size_t)b * (NPOS * 256);
    const u8* Vb = vf + (size_t)b * (NPOS * 256);

    // Q A-frags in regs (fp8: 8 bytes per kk)
    i64 qa[8];
    #pragma unroll
    for (int kk = 0; kk < 8; ++kk)
        qa[kk] = *(const i64*)(Qb + (size_t)(i0 + l16) * 256 + kk * 32 + g * 8);

    // per-lane pre-swizzled staging sources (advance per iter: K += 16KB, V += 64B)
    int stg_base = sp * 65536;                    // buf d adds d*32768
    const u8* ksrcq[4]; const u8* vsrcq[4];
    {
        int j0 = sp * 3456;
        #pragma unroll
        for (int q = 0; q < 4; ++q) {
            int o = (q * 4 + qg) * 1024 + lane * 16;
            ksrcq[q] = Kb + j0 * 256 + (o ^ (((o >> 8) & 7) << 4));
            int cc = o >> 6;
            vsrcq[q] = Vb + (size_t)cc * NPOS + j0 + ((o & 63) ^ ((cc & 3) << 4));
        }
    }
    // prologue: stage iter 0 into buf 0
    #pragma unroll
    for (int q = 0; q < 4; ++q) {
        gld16(ksrcq[q], smem + stg_base + (q * 4 + qg) * 1024);
        gld16(vsrcq[q], smem + stg_base + 16384 + (q * 4 + qg) * 1024);
        ksrcq[q] += 16384; vsrcq[q] += 64;
    }

    f32x4 oacc[16];
    #pragma unroll
    for (int cf = 0; cf < 16; ++cf) oacc[cf] = (f32x4){0.f,0.f,0.f,0.f};
    float m[4], lsum[4];
    #pragma unroll
    for (int r = 0; r < 4; ++r) { m[r] = -INFINITY; lsum[r] = 0.f; }
    int plo = PLDS_OFF + w * 1152;                // per-wave P tile [16][72] fp8

    __syncthreads();

    for (int it = 0; it < 54; ++it) {
        int cur = it & 1;
        if (it < 53) {                            // stage next tile (overlaps compute)
            int db = stg_base + (cur ^ 1) * 32768;
            #pragma unroll
            for (int q = 0; q < 4; ++q) {
                gld16(ksrcq[q], smem + db + (q * 4 + qg) * 1024);
                gld16(vsrcq[q], smem + db + 16384 + (q * 4 + qg) * 1024);
                ksrcq[q] += 16384; vsrcq[q] += 64;
            }
        }
        int kb = stg_base + cur * 32768;
        int vb = kb + 16384;

        // QK^T: S tile 16 rows x 64 cols
        f32x4 s4[4];
        #pragma unroll
        for (int f = 0; f < 4; ++f) s4[f] = (f32x4){0.f,0.f,0.f,0.f};
        #pragma unroll
        for (int kk = 0; kk < 8; ++kk) {
            #pragma unroll
            for (int f = 0; f < 4; ++f) {
                int row = f * 16 + l16;
                int unit = 2 * kk + (g >> 1);
                int byt = row * 256 + ((unit ^ (row & 7)) << 4) + (g & 1) * 8;
                i64 kv = *(const i64*)(smem + kb + byt);
                s4[f] = MFMA8(qa[kk], kv, s4[f]);
            }
        }
        // online softmax (rows 4g+r, reduce over 16 lanes)
        float pmax[4];
        #pragma unroll
        for (int r = 0; r < 4; ++r) {
            float mx = fmaxf(fmaxf(s4[0][r], s4[1][r]), fmaxf(s4[2][r], s4[3][r]));
            #pragma unroll
            for (int off = 1; off < 16; off <<= 1) mx = fmaxf(mx, __shfl_xor(mx, off));
            pmax[r] = mx;
        }
        bool upd = false;
        #pragma unroll
        for (int r = 0; r < 4; ++r) if ((pmax[r] - m[r]) * K2 > 8.f) upd = true;
        if (__any(upd)) {                         // defer-max: p bounded by 2^8=256 < 448
            #pragma unroll
            for (int r = 0; r < 4; ++r) {
                float mn = fmaxf(m[r], pmax[r]);
                float al = __builtin_amdgcn_exp2f((m[r] - mn) * K2);
                m[r] = mn; lsum[r] *= al;
                #pragma unroll
                for (int cf = 0; cf < 16; ++cf) oacc[cf][r] *= al;
            }
        }
        #pragma unroll
        for (int r = 0; r < 4; ++r) {
            float rs = 0.f;
            #pragma unroll
            for (int fq = 0; fq < 4; ++fq) {
                float p = __builtin_amdgcn_exp2f((s4[fq][r] - m[r]) * K2);
                smem[plo + (4 * g + r) * 72 + fq * 16 + l16] = (char)p2fp8(p);
                rs += p;
            }
            #pragma unroll
            for (int off = 1; off < 16; off <<= 1) rs += __shfl_xor(rs, off);
            lsum[r] += rs;
        }
        // PV: O += P * V^T  (A = P fp8 from LDS, B = V fp8 staged)
        #pragma unroll
        for (int kk2 = 0; kk2 < 2; ++kk2) {
            i64 pa = *(const i64*)(smem + plo + l16 * 72 + kk2 * 32 + g * 8);
            #pragma unroll
            for (int cf = 0; cf < 16; ++cf) {
                int cc = cf * 16 + l16;
                int unit = 2 * kk2 + (g >> 1);
                int byt = cc * 64 + ((unit ^ (cc & 3)) << 4) + (g & 1) * 8;
                i64 vv8 = *(const i64*)(smem + vb + byt);
                oacc[cf] = MFMA8(pa, vv8, oacc[cf]);
            }
        }
        __syncthreads();                          // drains staging vmcnt + buffer handoff
    }

    // ----- combine the two KV splits (waves w and w+4 share rows) -----
    float* smf = (float*)(smem + SM_OFF);         // [8][16][{m,l}]
    if (l16 == 0) {
        #pragma unroll
        for (int r = 0; r < 4; ++r) {
            smf[(w * 16 + 4 * g + r) * 2]     = m[r];
            smf[(w * 16 + 4 * g + r) * 2 + 1] = lsum[r];
        }
    }
    __syncthreads();
    float wsc[4], Linv[4];
    #pragma unroll
    for (int r = 0; r < 4; ++r) {
        int row = 4 * g + r;
        float m0 = smf[(qg * 16 + row) * 2],       l0 = smf[(qg * 16 + row) * 2 + 1];
        float m1 = smf[((qg + 4) * 16 + row) * 2], l1 = smf[((qg + 4) * 16 + row) * 2 + 1];
        float M  = fmaxf(m0, m1);
        float w0 = __builtin_amdgcn_exp2f((m0 - M) * K2);
        float w1 = __builtin_amdgcn_exp2f((m1 - M) * K2);
        wsc[r]  = sp ? w1 : w0;
        Linv[r] = 1.f / (l0 * w0 + l1 * w1);
    }
    float* cbuf = (float*)smem;                   // overlay on dead staging: [4][16][256] f32
    if (sp == 1) {
        #pragma unroll
        for (int cf = 0; cf < 16; ++cf)
            #pragma unroll
            for (int r = 0; r < 4; ++r)
                cbuf[(qg * 16 + 4 * g + r) * 256 + cf * 16 + l16] = oacc[cf][r] * wsc[r];
    }
    __syncthreads();
    if (sp == 0) {
        size_t ob = ((size_t)b * NPOS + i0) * C;
        #pragma unroll
        for (int cf = 0; cf < 16; ++cf)
            #pragma unroll
            for (int r = 0; r < 4; ++r) {
                float vfin = (oacc[cf][r] * wsc[r] +
                              cbuf[(qg * 16 + 4 * g + r) * 256 + cf * 16 + l16]) * Linv[r];
                oo[ob + (size_t)(4 * g + r) * C + cf * 16 + l16] = f2bf(vfin);
            }
    }
}

// ---------------- proj + bias + residual, coalesced via LDS transpose ----------------
__global__ __launch_bounds__(256) void proj(const unsigned short* oo, const unsigned short* wbf,
                                            const float* bp, const float* x, float* out) {
    int t = blockIdx.x;                  // 2 b * 108 pt * 4 ot = 864
    int b = t / 432; int rem2 = t % 432;
    int pt = rem2 >> 2; int ot = rem2 & 3;
    int lane = threadIdx.x & 63, w = threadIdx.x >> 6;
    int l16 = lane & 15, g = lane >> 4;
    const unsigned short* wpw = wbf + 196608;
    const unsigned short* arow = oo + ((size_t)b * NPOS + pt * 64 + w * 16 + l16) * C + g * 8;
    const unsigned short* brow = wpw + (ot * 64 + l16) * C + g * 8;
    f32x4 acc[4] = {{0.f,0.f,0.f,0.f},{0.f,0.f,0.f,0.f},{0.f,0.f,0.f,0.f},{0.f,0.f,0.f,0.f}};
    #pragma unroll
    for (int kk = 0; kk < 8; ++kk) {
        bf16x8 a = *(const bf16x8*)(arow + kk * 32);
        #pragma unroll
        for (int f = 0; f < 4; ++f) {
            bf16x8 bb = *(const bf16x8*)(brow + f * 16 * C + kk * 32);
            acc[f] = MFMA(a, bb, acc[f]);
        }
    }
    __shared__ float lt[64][72];
    #pragma unroll
    for (int f = 0; f < 4; ++f) {
        float bv = bp[ot * 64 + f * 16 + l16];
        #pragma unroll
        for (int r = 0; r < 4; ++r)
            lt[f * 16 + l16][w * 16 + 4 * g + r] = acc[f][r] + bv;
    }
    __syncthreads();
    int p0 = pt * 64;
    int f3 = p0 / HW; int sp0 = p0 - f3 * HW;     // 64 | 2304 so whole tile same f
    for (int it = 0; it < 16; ++it) {
        int ol = it * 4 + w;
        int pl = lane;
        size_t idx = ((size_t)(b * 3 + f3) * C + ot * 64 + ol) * HW + sp0 + pl;
        out[idx] = x[idx] + lt[ol][pl];
    }
}

extern "C" void kernel_launch(void* const* d_in, const int* in_sizes, int n_in,
                              void* d_out, int out_size, void* d_ws, size_t ws_size,
                              hipStream_t stream) {
    const float* x   = (const float*)d_in[0];
    const float* gsc = (const float*)d_in[1];
    const float* gbi = (const float*)d_in[2];
    const float* wq  = (const float*)d_in[3];
    const float* bq  = (const float*)d_in[4];
    const float* wk  = (const float*)d_in[5];
    const float* bk  = (const float*)d_in[6];
    const float* wv  = (const float*)d_in[7];
    const float* bv  = (const float*)d_in[8];
    const float* wp  = (const float*)d_in[9];
    const float* bp  = (const float*)d_in[10];

    char* ws = (char*)d_ws;
    unsigned short* wbf = (unsigned short*)(ws);             // 524288 B
    float* stats        = (float*)(ws + 524288);             // 64 B
    float* part         = (float*)(ws + 528384);             // 2048 B
    unsigned short* hn  = (unsigned short*)(ws + 532480);    // 7077888 B
    u8* qfp             = (u8*)(ws + 7610368);               // 1769472 B
    u8* kfp             = (u8*)(ws + 9379840);               // 1769472 B
    u8* vfp             = (u8*)(ws + 11149312);              // 1769472 B
    unsigned short* oo  = (unsigned short*)(ws + 12918784);  // 7077888 B -> end 19996672
    float* out = (float*)d_out;

    hipLaunchKernelGGL(wconv,    dim3(256),  dim3(256), 0, stream, wq, wk, wv, wp, wbf);
    hipLaunchKernelGGL(gn_stats, dim3(256),  dim3(256), 0, stream, x, part);
    hipLaunchKernelGGL(gn_fin,   dim3(1),    dim3(64),  0, stream, part, stats);
    hipLaunchKernelGGL(gn_apply, dim3(288),  dim3(256), 0, stream, x, stats, gsc, gbi, hn);
    hipLaunchKernelGGL(qk_gemm,  dim3(1728), dim3(256), 0, stream, hn, wbf, bq, bk, qfp, kfp);
    hipLaunchKernelGGL(v_gemm,   dim3(864),  dim3(256), 0, stream, hn, wbf, bv, vfp);
    hipLaunchKernelGGL(flash,    dim3(216),  dim3(512), 0, stream, qfp, kfp, vfp, oo);
    hipLaunchKernelGGL(proj,     dim3(864),  dim3(256), 0, stream, oo, wbf, bp, x, out);
}

// Round 3
// 257.964 us; speedup vs baseline: 3.6471x; 1.3044x over previous
//
#include <hip/hip_runtime.h>
#include <hip/hip_bf16.h>

#define NPOS 6912
#define HW   2304
#define C    256
#define EPSG 1e-6f
// softmax scale folded with log2(e): exp(s*0.0625) = exp2(s*K2)
#define K2 (0.0625f * 1.4426950408889634f)

typedef __attribute__((ext_vector_type(8))) short bf16x8;  // 8 bf16 in 4 VGPRs
typedef __attribute__((ext_vector_type(4))) float f32x4;
typedef long long i64;
typedef unsigned char u8;

__device__ __forceinline__ unsigned short f2bf(float f) {
    union { float f; unsigned int u; } v; v.f = f;
    unsigned int lsb = (v.u >> 16) & 1u;
    return (unsigned short)((v.u + 0x7fffu + lsb) >> 16);
}

// f32 -> fp8 e4m3fn (OCP), RNE, with subnormal handling. |f| <= ~3 here.
__device__ __forceinline__ u8 f2fp8(float f) {
    union { float f; unsigned u; } v; v.f = f;
    unsigned sgn = (v.u >> 24) & 0x80u;
    unsigned a = v.u & 0x7FFFFFFFu;
    if (a >= 0x3C800000u) {                       // |f| >= 2^-6 : normal
        unsigned r = a + 0x000FFFFFu + ((a >> 20) & 1u);
        return (u8)(sgn | ((r >> 20) - 0x3C0u));
    }
    union { unsigned u; float f; } w2; w2.u = a;
    int mnt = (int)rintf(w2.f * 512.0f);          // subnormal: step 2^-9
    return (u8)(sgn | (unsigned)mnt);
}

#define MFMA(a, b, c)  __builtin_amdgcn_mfma_f32_16x16x32_bf16((a), (b), (c), 0, 0, 0)
#define MFMA8(a, b, c) __builtin_amdgcn_mfma_f32_16x16x32_fp8_fp8((a), (b), (c), 0, 0, 0)

// async global->LDS, 16B per lane; dest must be wave-uniform base (lane*16 implicit)
__device__ __forceinline__ void gld16(const u8* g, const char* l) {
    __builtin_amdgcn_global_load_lds(
        (const __attribute__((address_space(1))) void*)(unsigned long long)g,
        (__attribute__((address_space(3))) void*)(unsigned int)(unsigned long long)l,
        16, 0, 0);
}

// ---------------- weights fp32 -> bf16 ----------------
__global__ void wconv(const float* wq, const float* wk, const float* wv, const float* wp,
                      unsigned short* wbf) {
    int i = blockIdx.x * 256 + threadIdx.x;        // 0..65535
    wbf[i]           = f2bf(wq[i]);
    wbf[65536 + i]   = f2bf(wk[i]);
    wbf[131072 + i]  = f2bf(wv[i]);
    wbf[196608 + i]  = f2bf(wp[i]);
}

// ---------------- GroupNorm stats (deterministic 2-stage) ----------------
__global__ __launch_bounds__(256) void gn_stats(const float* x, float* part) {
    int gid = blockIdx.x >> 5, slice = blockIdx.x & 31; // 8 groups x 32 slices
    int b = gid >> 2, grp = gid & 3;
    float s = 0.f, s2 = 0.f;
    for (int k = 0; k < 54; ++k) {
        int e = slice * 13824 + k * 256 + (int)threadIdx.x;   // 0..442367 per group
        int f = e / 147456; int r1 = e - f * 147456;
        int ch = r1 / HW;   int sp = r1 - ch * HW;
        float v = x[(size_t)((f * 2 + b) * C + grp * 64 + ch) * HW + sp];
        s += v; s2 += v * v;
    }
    #pragma unroll
    for (int off = 32; off; off >>= 1) { s += __shfl_xor(s, off); s2 += __shfl_xor(s2, off); }
    __shared__ float ls[8];
    int w = threadIdx.x >> 6;
    if ((threadIdx.x & 63) == 0) { ls[w * 2] = s; ls[w * 2 + 1] = s2; }
    __syncthreads();
    if (threadIdx.x == 0) {
        float t = 0.f, t2 = 0.f;
        for (int i = 0; i < 4; ++i) { t += ls[i * 2]; t2 += ls[i * 2 + 1]; }
        part[blockIdx.x * 2] = t; part[blockIdx.x * 2 + 1] = t2;
    }
}

__global__ void gn_fin(const float* part, float* stats) {
    int g = threadIdx.x; if (g >= 8) return;
    float s = 0.f, s2 = 0.f;
    for (int i = 0; i < 32; ++i) { s += part[(g * 32 + i) * 2]; s2 += part[(g * 32 + i) * 2 + 1]; }
    float mean = s / 442368.f;
    float var  = s2 / 442368.f - mean * mean;
    stats[g * 2] = mean; stats[g * 2 + 1] = rsqrtf(var + EPSG);
}

// ---------------- GN apply -> Hn (b, n, c) bf16, LDS transpose ----------------
__global__ __launch_bounds__(256) void gn_apply(const float* x, const float* stats,
                                                const float* gsc, const float* gbi,
                                                unsigned short* hn) {
    int blk = blockIdx.x;                 // 2*3*48 = 288
    int b = blk / 144; int f = (blk % 144) / 48; int y = blk % 48;
    int c = threadIdx.x;
    int gid = b * 4 + (c >> 6);
    float mean = stats[gid * 2], rsig = stats[gid * 2 + 1];
    float sc = gsc[c] * rsig, bi = gbi[c] - mean * sc;
    __shared__ unsigned short lds[48 * 256];
    const float* xr = x + (size_t)((f * 2 + b) * C + c) * HW + y * 48;
    #pragma unroll
    for (int xw = 0; xw < 48; xw += 4) {
        float4 v = *(const float4*)(xr + xw);
        lds[(xw + 0) * 256 + c] = f2bf(v.x * sc + bi);
        lds[(xw + 1) * 256 + c] = f2bf(v.y * sc + bi);
        lds[(xw + 2) * 256 + c] = f2bf(v.z * sc + bi);
        lds[(xw + 3) * 256 + c] = f2bf(v.w * sc + bi);
    }
    __syncthreads();
    size_t base = ((size_t)b * NPOS + f * HW + y * 48) * C;
    for (int xw = 0; xw < 48; ++xw)
        hn[base + (size_t)xw * C + threadIdx.x] = lds[xw * 256 + threadIdx.x];
}

// ---------------- Q/K GEMM: out(b,n,c) fp8 = Hn(b,n,c) x W^T + bias ----------------
__global__ __launch_bounds__(256) void qk_gemm(const unsigned short* hn, const unsigned short* wbf,
                                               const float* bq, const float* bk,
                                               u8* qfp, u8* kfp) {
    int t = blockIdx.x;                  // 2 sel * 2 b * 108 pt * 4 ot = 1728
    int sel = t / 864; int rem = t % 864;
    int b = rem / 432;  int rem2 = rem % 432;
    int pt = rem2 >> 2; int ot = rem2 & 3;
    int lane = threadIdx.x & 63, w = threadIdx.x >> 6;
    int l16 = lane & 15, g = lane >> 4;
    const unsigned short* wsel = wbf + sel * 65536;
    const float* bias = sel ? bk : bq;
    u8* out = sel ? kfp : qfp;
    const unsigned short* arow = hn + ((size_t)b * NPOS + pt * 64 + w * 16 + l16) * C + g * 8;
    const unsigned short* brow = wsel + (ot * 64 + l16) * C + g * 8;
    f32x4 acc[4] = {{0.f,0.f,0.f,0.f},{0.f,0.f,0.f,0.f},{0.f,0.f,0.f,0.f},{0.f,0.f,0.f,0.f}};
    #pragma unroll
    for (int kk = 0; kk < 8; ++kk) {
        bf16x8 a = *(const bf16x8*)(arow + kk * 32);
        #pragma unroll
        for (int f = 0; f < 4; ++f) {
            bf16x8 bb = *(const bf16x8*)(brow + f * 16 * C + kk * 32);
            acc[f] = MFMA(a, bb, acc[f]);
        }
    }
    size_t obase = ((size_t)b * NPOS + pt * 64 + w * 16) * C + ot * 64;
    #pragma unroll
    for (int f = 0; f < 4; ++f) {
        float bv = bias[ot * 64 + f * 16 + l16];
        #pragma unroll
        for (int r = 0; r < 4; ++r)
            out[obase + (size_t)(4 * g + r) * C + f * 16 + l16] = f2fp8(acc[f][r] + bv);
    }
}

// ---------------- V GEMM: V(b,c,n) fp8 = Wv x Hn^T + bias ----------------
__global__ __launch_bounds__(256) void v_gemm(const unsigned short* hn, const unsigned short* wbf,
                                              const float* bvp, u8* vfp) {
    int t = blockIdx.x;                  // 2 b * 4 ot * 108 pt = 864
    int b = t / 432; int rem2 = t % 432;
    int ot = rem2 / 108; int pt = rem2 % 108;
    int lane = threadIdx.x & 63, w = threadIdx.x >> 6;
    int l16 = lane & 15, g = lane >> 4;
    const unsigned short* wvw = wbf + 131072;
    const unsigned short* arow = wvw + (ot * 64 + w * 16 + l16) * C + g * 8;
    const unsigned short* brow = hn + ((size_t)b * NPOS + pt * 64 + l16) * C + g * 8;
    f32x4 acc[4] = {{0.f,0.f,0.f,0.f},{0.f,0.f,0.f,0.f},{0.f,0.f,0.f,0.f},{0.f,0.f,0.f,0.f}};
    #pragma unroll
    for (int kk = 0; kk < 8; ++kk) {
        bf16x8 a = *(const bf16x8*)(arow + kk * 32);
        #pragma unroll
        for (int f = 0; f < 4; ++f) {
            bf16x8 bb = *(const bf16x8*)(brow + f * 16 * C + kk * 32);
            acc[f] = MFMA(a, bb, acc[f]);
        }
    }
    #pragma unroll
    for (int f = 0; f < 4; ++f) {
        #pragma unroll
        for (int r = 0; r < 4; ++r) {
            int o = ot * 64 + w * 16 + 4 * g + r;
            vfp[((size_t)b * C + o) * NPOS + pt * 64 + f * 16 + l16] = f2fp8(acc[f][r] + bvp[o]);
        }
    }
}

// ---------------- flash attention (fp8), swapped QK^T, in-register P ----------------
// 216 blocks x 512 threads. blk%8 -> XCD; batch pinned to XCD half (K+V fp8 = 3.54MB < 4MB L2).
// 8 waves: wave w: split sp=w>>2 (KV half), q-group qg=w&3 (16 q rows). Double-buffered LDS.
// S^T = mfma(K,Q): lane l16 owns q-row l16; softmax = 2 shfl_xor; P->fp8 via cvt_pk; P->A-frag
// via 8 shfl. K swizzle: granule ^= (row&7) (b64-min banking). V swizzle: pos^((pos>>3)&7).
#define SMEM_BYTES 132096
#define SM_OFF     131072

__global__ __launch_bounds__(512) void flash(const u8* qf, const u8* kf, const u8* vf,
                                             unsigned short* oo) {
    __shared__ char smem[SMEM_BYTES];
    int blk = blockIdx.x;
    int x = blk & 7, t = blk >> 3;                // x = XCD slot
    int b = x >> 2, qtile = t * 4 + (x & 3);      // batch pinned to XCD half
    int tid = (int)threadIdx.x;
    int lane = tid & 63, w = tid >> 6;
    int l16 = lane & 15, g = lane >> 4;
    int sp = w >> 2, qg = w & 3;
    int i0 = qtile * 64 + qg * 16;

    const u8* Qb = qf + (size_t)b * (NPOS * 256);
    const u8* Kb = kf + (size_t)b * (NPOS * 256);
    const u8* Vb = vf + (size_t)b * (NPOS * 256);

    // Q B-frags in regs (B-frag layout == A-frag layout: col=l16, k=g*8+j)
    i64 qa[8];
    #pragma unroll
    for (int kk = 0; kk < 8; ++kk)
        qa[kk] = *(const i64*)(Qb + (size_t)(i0 + l16) * 256 + kk * 32 + g * 8);

    // per-lane read-address precompute (swizzled; ds offset imm folds f*4096 / cf*1024)
    int gh = g >> 1, kh = (g & 1) * 8;
    int C4 = (l16 & 7) << 4;
    int kaddr[8];
    #pragma unroll
    for (int kk = 0; kk < 8; ++kk)
        kaddr[kk] = l16 * 256 + (((2 * kk + gh) << 4) ^ C4) + kh;
    int D3 = (l16 >> 1) & 7;
    int vaddr[2];
    #pragma unroll
    for (int kk2 = 0; kk2 < 2; ++kk2)
        vaddr[kk2] = (((4 * l16 + 2 * kk2 + gh) ^ D3) << 4) + kh;
    int srcA = (g & 1) * 32 + l16;                // P-shfl sources
    int srcB = srcA + 16;
    int sbase = 20 * g;                           // alpha-fetch base (lane with l16 = 4g+r)

    // per-lane pre-swizzled staging sources (advance per iter: K += 16KB, V += 64B)
    int stg_base = sp * 65536;                    // buf d adds d*32768
    const u8* ksrcq[4]; const u8* vsrcq[4];
    {
        int j0 = sp * 3456;
        #pragma unroll
        for (int q = 0; q < 4; ++q) {
            int o = (q * 4 + qg) * 1024 + lane * 16;
            ksrcq[q] = Kb + j0 * 256 + (o ^ (((o >> 8) & 7) << 4));
            int p = o >> 4;                       // granule slot in V area
            int id = p ^ ((p >> 3) & 7);
            vsrcq[q] = Vb + (size_t)(id >> 2) * NPOS + j0 + (id & 3) * 16;
        }
    }
    // prologue: stage iter 0 into buf 0
    #pragma unroll
    for (int q = 0; q < 4; ++q) {
        gld16(ksrcq[q], smem + stg_base + (q * 4 + qg) * 1024);
        gld16(vsrcq[q], smem + stg_base + 16384 + (q * 4 + qg) * 1024);
        ksrcq[q] += 16384; vsrcq[q] += 64;
    }

    f32x4 oacc[16];
    #pragma unroll
    for (int cf = 0; cf < 16; ++cf) oacc[cf] = (f32x4){0.f,0.f,0.f,0.f};
    float m = -INFINITY, lsum = 0.f;              // for q-row = l16

    __syncthreads();

    for (int it = 0; it < 54; ++it) {
        int cur = it & 1;
        if (it < 53) {                            // stage next tile (overlaps compute)
            int db = stg_base + (cur ^ 1) * 32768;
            #pragma unroll
            for (int q = 0; q < 4; ++q) {
                gld16(ksrcq[q], smem + db + (q * 4 + qg) * 1024);
                gld16(vsrcq[q], smem + db + 16384 + (q * 4 + qg) * 1024);
                ksrcq[q] += 16384; vsrcq[q] += 64;
            }
        }
        int kb = stg_base + cur * 32768;
        int vb = kb + 16384;

        // S^T = K * Q^T : lane holds S[q=l16][k=f*16+4g+r]
        f32x4 s4[4];
        #pragma unroll
        for (int f = 0; f < 4; ++f) s4[f] = (f32x4){0.f,0.f,0.f,0.f};
        const char* kp = smem + kb;
        __builtin_amdgcn_s_setprio(1);
        #pragma unroll
        for (int kk = 0; kk < 8; ++kk) {
            const char* ka = kp + kaddr[kk];
            #pragma unroll
            for (int f = 0; f < 4; ++f) {
                i64 kv = *(const i64*)(ka + f * 4096);
                s4[f] = MFMA8(kv, qa[kk], s4[f]);
            }
        }
        __builtin_amdgcn_s_setprio(0);

        // online softmax, all in registers (row owner = lane; replicated over g)
        float pmax = s4[0][0];
        #pragma unroll
        for (int f = 0; f < 4; ++f)
            #pragma unroll
            for (int r = 0; r < 4; ++r) pmax = fmaxf(pmax, s4[f][r]);
        pmax = fmaxf(pmax, __shfl_xor(pmax, 16));
        pmax = fmaxf(pmax, __shfl_xor(pmax, 32));
        bool upd = (pmax - m) * K2 > 8.f;
        if (__any(upd)) {                         // defer-max: p bounded by 2^8=256 < 448
            float mn = fmaxf(m, pmax);
            float al = __builtin_amdgcn_exp2f((m - mn) * K2);
            m = mn; lsum *= al;
            #pragma unroll
            for (int r = 0; r < 4; ++r) {
                float ar = __shfl(al, sbase + r);  // alpha of row 4g+r
                #pragma unroll
                for (int cf = 0; cf < 16; ++cf) oacc[cf][r] *= ar;
            }
        }
        float rs = 0.f;
        int d_[4];
        #pragma unroll
        for (int f = 0; f < 4; ++f) {
            float p0 = __builtin_amdgcn_exp2f((s4[f][0] - m) * K2);
            float p1 = __builtin_amdgcn_exp2f((s4[f][1] - m) * K2);
            float p2 = __builtin_amdgcn_exp2f((s4[f][2] - m) * K2);
            float p3 = __builtin_amdgcn_exp2f((s4[f][3] - m) * K2);
            rs += (p0 + p1) + (p2 + p3);
            int lo = __builtin_amdgcn_cvt_pk_fp8_f32(p0, p1, 0, false);
            d_[f]  = __builtin_amdgcn_cvt_pk_fp8_f32(p2, p3, lo, true);
        }
        rs += __shfl_xor(rs, 16);
        rs += __shfl_xor(rs, 32);
        lsum += rs;

        // PV: O += P * V ; A-frag of P assembled via shfl from d_
        const char* vp = smem + vb;
        #pragma unroll
        for (int kk2 = 0; kk2 < 2; ++kk2) {
            int lo0 = __shfl(d_[2 * kk2],     srcA);
            int lo1 = __shfl(d_[2 * kk2 + 1], srcA);
            int hi0 = __shfl(d_[2 * kk2],     srcB);
            int hi1 = __shfl(d_[2 * kk2 + 1], srcB);
            unsigned int plo = (unsigned int)(gh ? lo1 : lo0);
            unsigned int phi = (unsigned int)(gh ? hi1 : hi0);
            i64 pa = (i64)plo | ((i64)phi << 32);
            const char* va = vp + vaddr[kk2];
            __builtin_amdgcn_s_setprio(1);
            #pragma unroll
            for (int cf = 0; cf < 16; ++cf) {
                i64 vv8 = *(const i64*)(va + cf * 1024);
                oacc[cf] = MFMA8(pa, vv8, oacc[cf]);
            }
            __builtin_amdgcn_s_setprio(0);
        }
        __syncthreads();                          // drains staging vmcnt + buffer handoff
    }

    // ----- combine the two KV splits (waves w and w+4 share rows) -----
    float* smf = (float*)(smem + SM_OFF);         // [8][16][{m,l}]
    if (g == 0) {
        smf[(w * 16 + l16) * 2]     = m;
        smf[(w * 16 + l16) * 2 + 1] = lsum;
    }
    __syncthreads();
    float wsc[4], Linv[4];
    #pragma unroll
    for (int r = 0; r < 4; ++r) {
        int row = 4 * g + r;
        float m0 = smf[(qg * 16 + row) * 2],       l0 = smf[(qg * 16 + row) * 2 + 1];
        float m1 = smf[((qg + 4) * 16 + row) * 2], l1 = smf[((qg + 4) * 16 + row) * 2 + 1];
        float M  = fmaxf(m0, m1);
        float w0 = __builtin_amdgcn_exp2f((m0 - M) * K2);
        float w1 = __builtin_amdgcn_exp2f((m1 - M) * K2);
        wsc[r]  = sp ? w1 : w0;
        Linv[r] = 1.f / (l0 * w0 + l1 * w1);
    }
    float* cbuf = (float*)smem;                   // overlay on dead staging: [4][16][256] f32
    if (sp == 1) {
        #pragma unroll
        for (int cf = 0; cf < 16; ++cf)
            #pragma unroll
            for (int r = 0; r < 4; ++r)
                cbuf[(qg * 16 + 4 * g + r) * 256 + cf * 16 + l16] = oacc[cf][r] * wsc[r];
    }
    __syncthreads();
    if (sp == 0) {
        size_t ob = ((size_t)b * NPOS + i0) * C;
        #pragma unroll
        for (int cf = 0; cf < 16; ++cf)
            #pragma unroll
            for (int r = 0; r < 4; ++r) {
                float vfin = (oacc[cf][r] * wsc[r] +
                              cbuf[(qg * 16 + 4 * g + r) * 256 + cf * 16 + l16]) * Linv[r];
                oo[ob + (size_t)(4 * g + r) * C + cf * 16 + l16] = f2bf(vfin);
            }
    }
}

// ---------------- proj + bias + residual, coalesced via LDS transpose ----------------
__global__ __launch_bounds__(256) void proj(const unsigned short* oo, const unsigned short* wbf,
                                            const float* bp, const float* x, float* out) {
    int t = blockIdx.x;                  // 2 b * 108 pt * 4 ot = 864
    int b = t / 432; int rem2 = t % 432;
    int pt = rem2 >> 2; int ot = rem2 & 3;
    int lane = threadIdx.x & 63, w = threadIdx.x >> 6;
    int l16 = lane & 15, g = lane >> 4;
    const unsigned short* wpw = wbf + 196608;
    const unsigned short* arow = oo + ((size_t)b * NPOS + pt * 64 + w * 16 + l16) * C + g * 8;
    const unsigned short* brow = wpw + (ot * 64 + l16) * C + g * 8;
    f32x4 acc[4] = {{0.f,0.f,0.f,0.f},{0.f,0.f,0.f,0.f},{0.f,0.f,0.f,0.f},{0.f,0.f,0.f,0.f}};
    #pragma unroll
    for (int kk = 0; kk < 8; ++kk) {
        bf16x8 a = *(const bf16x8*)(arow + kk * 32);
        #pragma unroll
        for (int f = 0; f < 4; ++f) {
            bf16x8 bb = *(const bf16x8*)(brow + f * 16 * C + kk * 32);
            acc[f] = MFMA(a, bb, acc[f]);
        }
    }
    __shared__ float lt[64][72];
    #pragma unroll
    for (int f = 0; f < 4; ++f) {
        float bv = bp[ot * 64 + f * 16 + l16];
        #pragma unroll
        for (int r = 0; r < 4; ++r)
            lt[f * 16 + l16][w * 16 + 4 * g + r] = acc[f][r] + bv;
    }
    __syncthreads();
    int p0 = pt * 64;
    int f3 = p0 / HW; int sp0 = p0 - f3 * HW;     // 64 | 2304 so whole tile same f
    for (int it = 0; it < 16; ++it) {
        int ol = it * 4 + w;
        int pl = lane;
        size_t idx = ((size_t)(b * 3 + f3) * C + ot * 64 + ol) * HW + sp0 + pl;
        out[idx] = x[idx] + lt[ol][pl];
    }
}

extern "C" void kernel_launch(void* const* d_in, const int* in_sizes, int n_in,
                              void* d_out, int out_size, void* d_ws, size_t ws_size,
                              hipStream_t stream) {
    const float* x   = (const float*)d_in[0];
    const float* gsc = (const float*)d_in[1];
    const float* gbi = (const float*)d_in[2];
    const float* wq  = (const float*)d_in[3];
    const float* bq  = (const float*)d_in[4];
    const float* wk  = (const float*)d_in[5];
    const float* bk  = (const float*)d_in[6];
    const float* wv  = (const float*)d_in[7];
    const float* bv  = (const float*)d_in[8];
    const float* wp  = (const float*)d_in[9];
    const float* bp  = (const float*)d_in[10];

    char* ws = (char*)d_ws;
    unsigned short* wbf = (unsigned short*)(ws);             // 524288 B
    float* stats        = (float*)(ws + 524288);             // 64 B
    float* part         = (float*)(ws + 528384);             // 2048 B
    unsigned short* hn  = (unsigned short*)(ws + 532480);    // 7077888 B
    u8* qfp             = (u8*)(ws + 7610368);               // 1769472 B
    u8* kfp             = (u8*)(ws + 9379840);               // 1769472 B
    u8* vfp             = (u8*)(ws + 11149312);              // 1769472 B
    unsigned short* oo  = (unsigned short*)(ws + 12918784);  // 7077888 B -> end 19996672
    float* out = (float*)d_out;

    hipLaunchKernelGGL(wconv,    dim3(256),  dim3(256), 0, stream, wq, wk, wv, wp, wbf);
    hipLaunchKernelGGL(gn_stats, dim3(256),  dim3(256), 0, stream, x, part);
    hipLaunchKernelGGL(gn_fin,   dim3(1),    dim3(64),  0, stream, part, stats);
    hipLaunchKernelGGL(gn_apply, dim3(288),  dim3(256), 0, stream, x, stats, gsc, gbi, hn);
    hipLaunchKernelGGL(qk_gemm,  dim3(1728), dim3(256), 0, stream, hn, wbf, bq, bk, qfp, kfp);
    hipLaunchKernelGGL(v_gemm,   dim3(864),  dim3(256), 0, stream, hn, wbf, bv, vfp);
    hipLaunchKernelGGL(flash,    dim3(216),  dim3(512), 0, stream, qfp, kfp, vfp, oo);
    hipLaunchKernelGGL(proj,     dim3(864),  dim3(256), 0, stream, oo, wbf, bp, x, out);
}